// Round 7
// baseline (479.320 us; speedup 1.0000x reference)
//
#include <hip/hip_runtime.h>

#define NN 50000
#define NE 600000
#define DD 128
#define HD 512
#define NB 196  // (NN+255)/256 scan blocks

typedef unsigned short u16;
typedef __attribute__((ext_vector_type(8))) short short8;
typedef __attribute__((ext_vector_type(4))) short short4v;
typedef __attribute__((ext_vector_type(4))) float floatx4;

__device__ inline float b2f(u16 u) {
  return __uint_as_float(((unsigned int)u) << 16);
}
__device__ inline u16 f2b(float f) {
  unsigned int u = __float_as_uint(f);
  u = u + 0x7FFFu + ((u >> 16) & 1u);   // round-to-nearest-even
  return (u16)(u >> 16);
}

// async 16B global->LDS DMA (gfx950). LDS dest = wave-uniform base + lane*16.
__device__ inline void load_lds16(const u16* g, u16* l) {
  __builtin_amdgcn_global_load_lds(
      (const __attribute__((address_space(1))) unsigned int*)(uintptr_t)g,
      (__attribute__((address_space(3))) unsigned int*)(uintptr_t)l,
      16, 0, 0);
}

__global__ void zero_k(int* __restrict__ p, int n) {
  int i = blockIdx.x * 256 + threadIdx.x;
  if (i < n) p[i] = 0;
}

// -------- prep: x fp32 -> bf16 (into dead rst0 space) + both W transposes ---
// x cvt here makes GEMM1 structurally identical to GEMM2 (bf16 A path, no f2b
// in the inner loop) and halves its A-read bytes. Rounding identical to the
// old in-register cvt. Blocks [0,12500): x (4 elems/thread); then W0, W1.
__global__ void prep_k(const float* __restrict__ x, u16* __restrict__ xb,
                       const float* __restrict__ W0, u16* __restrict__ Wt0,
                       const float* __restrict__ W1, u16* __restrict__ Wt1) {
  const int XB = (NN * 256) / 1024;   // 12500
  int b = blockIdx.x;
  if (b < XB) {
    const int i = (b * 256 + threadIdx.x) * 4;
    floatx4 v = *(const floatx4*)(x + i);
    u16 o[4];
#pragma unroll
    for (int j = 0; j < 4; ++j) o[j] = f2b(v[j]);
    *(short4v*)(xb + i) = *(short4v*)o;
  } else if (b < XB + 512) {
    const int idx = (b - XB) * 256 + threadIdx.x;   // < 256*512
    const int k = idx >> 9, n = idx & 511;
    Wt0[n * 256 + k] = f2b(W0[idx]);
  } else {
    const int idx = (b - XB - 512) * 256 + threadIdx.x;   // < 512*512
    const int k = idx >> 9, n = idx & 511;
    Wt1[n * 512 + k] = f2b(W1[idx]);
  }
}

// ---------------- CSR build (multi-block scan) ----------------
__global__ void count_k(const int* __restrict__ dst, int* __restrict__ counts) {
  int e = blockIdx.x * 256 + threadIdx.x;
  if (e < NE) atomicAdd(&counts[dst[e]], 1);
}

__global__ __launch_bounds__(256) void blockscan_k(const int* __restrict__ counts,
                                                   int* __restrict__ rowp,
                                                   int* __restrict__ bsums) {
  __shared__ int tmp[256];
  int t = threadIdx.x;
  int i = blockIdx.x * 256 + t;
  int v = (i < NN) ? counts[i] : 0;
  tmp[t] = v;
  __syncthreads();
  for (int off = 1; off < 256; off <<= 1) {
    int u = (t >= off) ? tmp[t - off] : 0;
    __syncthreads();
    tmp[t] += u;
    __syncthreads();
  }
  if (i < NN) rowp[i] = tmp[t] - v;   // block-local exclusive
  if (t == 255) bsums[blockIdx.x] = tmp[t];
}

// addoff with the bsums scan inlined (every block redundantly scans the 196
// block sums in LDS, then adds its own offset). Replaces bscan + addoff.
__global__ __launch_bounds__(256) void addoff_k(int* __restrict__ rowp,
                                                int* __restrict__ cursor,
                                                const int* __restrict__ bsums) {
  __shared__ int tmp[256];
  int t = threadIdx.x;
  int v = (t < NB) ? bsums[t] : 0;
  tmp[t] = v;
  __syncthreads();
  for (int off = 1; off < 256; off <<= 1) {
    int u = (t >= off) ? tmp[t - off] : 0;
    __syncthreads();
    tmp[t] += u;
    __syncthreads();
  }
  const int boff = (blockIdx.x == 0) ? 0 : tmp[blockIdx.x - 1];
  int i = blockIdx.x * 256 + t;
  if (i < NN) {
    int v2 = rowp[i] + boff;
    rowp[i] = v2;
    cursor[i] = v2;
  }
  if (i == 0) rowp[NN] = NE;
}

__global__ void scatter_k(const int* __restrict__ src, const int* __restrict__ dst,
                          int* __restrict__ cursor, int* __restrict__ csrs) {
  int e = blockIdx.x * 256 + threadIdx.x;
  if (e < NE) {
    int d = dst[e];
    int pos = atomicAdd(&cursor[d], 1);
    csrs[pos] = src[e];
  }
}

// ---------------- GEMM + el/er epilogue (fragment-reuse redesign) -----------
// A[M,K] bf16 row-major, Wt[512,K] bf16 pre-transposed.
// R5 analysis: old wave tile (16 rows x 256 cols) had 1 ds_read_b128 per MFMA
// (16 unique B-frags per K-step, A in registers) -> LDS-issue-bound at
// 12cy/ds_read vs 4.85cy/MFMA. New tiling:
//   block = 64 rows x 512 cols (full N), 8 waves; wave = 64 rows x 64 cols.
//   Per K-step per wave: 4 A-frag + 4 B-frag ds_reads feed 16 MFMAs (1:2).
//   A staged to LDS by DMA like B (same 64B-row swizzle; rows clamp in the
//   per-lane SOURCE address, dest stays linear).
// Also: no col-half split -> A rows read once per GEMM (-100MB HBM total).
// LDS: B 2x32KB + A 2x4KB + epilogue 4KB = 76KB -> 2 blocks/CU.
// 1-barrier 2-phase per K-step (proven R5): stage(t+1)->buf[(t+1)&1],
// compute buf[t&1], vmcnt(0)+barrier. Hazard-safe: stage(t+2) (issued in step
// t+1) targets buf[t&1], whose step-t reads completed before the t->t+1
// barrier (lgkmcnt before MFMA use precedes barrier arrival).
// el/er: wave w covers cols [w*64,w*64+64) = half of head w>>1; partial sums
// combined across wave pairs through LDS (no atomics).
template <int K>
__global__ __launch_bounds__(512, 4) void gemm_el_er(
    const u16* __restrict__ Ab, const u16* __restrict__ Wt,
    const float* __restrict__ al, const float* __restrict__ ar,
    u16* __restrict__ h, float* __restrict__ el, float* __restrict__ er) {
  __shared__ u16 Ws[2][512 * 32];     // 2 x 32 KB
  __shared__ u16 As[2][64 * 32];      // 2 x 4 KB
  __shared__ float ep_el[8][64];      // 2 KB
  __shared__ float ep_er[8][64];      // 2 KB

  const int tid = threadIdx.x;
  const int w = tid >> 6, lane = tid & 63, quad = lane >> 4, l16 = lane & 15;
  const long abase = (long)blockIdx.x * 64;

  floatx4 acc[4][4] = {};   // [row-frag][col-frag]

  // staging geometry (64B rows, 4x16B chunks, XOR swizzle p ^ ((r>>1)&3)):
  // lane covers row rbase+(lane>>2), position lane&3, source chunk q8/16.
  const int drow = lane >> 2;
  const int q8 = ((lane & 3) ^ ((lane >> 3) & 3)) * 8;   // u16 off in source
  const int p4 = (quad ^ ((l16 >> 1) & 3)) * 8;          // u16 off in LDS row

  // A staging source row (per-lane, clamped; DMA dest stays linear).
  const long asrow_ = abase + w * 16 + drow;
  const long asrow = (asrow_ < NN) ? asrow_ : (NN - 1);

#define ISSUE_STAGE(kk, sel)                                                \
  {                                                                         \
    _Pragma("unroll") for (int rr = 0; rr < 4; ++rr) {                      \
      const int rbase = rr * 128 + w * 16;                                  \
      load_lds16(Wt + (long)(rbase + drow) * K + (kk) + q8,                 \
                 &Ws[sel][rbase * 32]);                                     \
    }                                                                       \
    if (w < 4) {                                                            \
      load_lds16(Ab + asrow * K + (kk) + q8, &As[sel][(w * 16) * 32]);      \
    }                                                                       \
  }

#define COMPUTE(sel)                                                        \
  {                                                                         \
    short8 a0 = *(const short8*)(&As[sel][(0 * 16 + l16) * 32 + p4]);       \
    short8 a1 = *(const short8*)(&As[sel][(1 * 16 + l16) * 32 + p4]);       \
    short8 a2 = *(const short8*)(&As[sel][(2 * 16 + l16) * 32 + p4]);       \
    short8 a3 = *(const short8*)(&As[sel][(3 * 16 + l16) * 32 + p4]);       \
    _Pragma("unroll") for (int cf = 0; cf < 4; ++cf) {                      \
      short8 bf =                                                           \
          *(const short8*)(&Ws[sel][(w * 64 + cf * 16 + l16) * 32 + p4]);   \
      acc[0][cf] =                                                          \
          __builtin_amdgcn_mfma_f32_16x16x32_bf16(a0, bf, acc[0][cf], 0, 0, 0); \
      acc[1][cf] =                                                          \
          __builtin_amdgcn_mfma_f32_16x16x32_bf16(a1, bf, acc[1][cf], 0, 0, 0); \
      acc[2][cf] =                                                          \
          __builtin_amdgcn_mfma_f32_16x16x32_bf16(a2, bf, acc[2][cf], 0, 0, 0); \
      acc[3][cf] =                                                          \
          __builtin_amdgcn_mfma_f32_16x16x32_bf16(a3, bf, acc[3][cf], 0, 0, 0); \
    }                                                                       \
  }

  const int T = K / 32;   // 8 or 16

  ISSUE_STAGE(0, 0);
  asm volatile("s_waitcnt vmcnt(0)" ::: "memory");
  __builtin_amdgcn_s_barrier();

#pragma unroll
  for (int t = 0; t < T; ++t) {
    if (t + 1 < T) ISSUE_STAGE((t + 1) * 32, (t + 1) & 1);
    COMPUTE(t & 1);
    asm volatile("s_waitcnt vmcnt(0)" ::: "memory");
    __builtin_amdgcn_s_barrier();
  }

#undef ISSUE_STAGE
#undef COMPUTE

  // ---- epilogue: h store + el/er partials (wave's 64-col slice) ----
  float alv[4], arv[4];
#pragma unroll
  for (int cf = 0; cf < 4; ++cf) {
    const int col = w * 64 + cf * 16 + l16;
    alv[cf] = al[col];
    arv[cf] = ar[col];
  }

#pragma unroll
  for (int rf = 0; rf < 4; ++rf) {
#pragma unroll
    for (int reg = 0; reg < 4; ++reg) {
      const long r = abase + rf * 16 + quad * 4 + reg;
      if (r < NN) {
#pragma unroll
        for (int cf = 0; cf < 4; ++cf)
          h[r * HD + w * 64 + cf * 16 + l16] = f2b(acc[rf][cf][reg]);
      }
      float pe = 0.f, pr = 0.f;
#pragma unroll
      for (int cf = 0; cf < 4; ++cf) {
        pe += acc[rf][cf][reg] * alv[cf];
        pr += acc[rf][cf][reg] * arv[cf];
      }
#pragma unroll
      for (int m = 1; m < 16; m <<= 1) {
        pe += __shfl_xor(pe, m, 64);
        pr += __shfl_xor(pr, m, 64);
      }
      if (l16 == 0) {
        ep_el[w][rf * 16 + quad * 4 + reg] = pe;
        ep_er[w][rf * 16 + quad * 4 + reg] = pr;
      }
    }
  }
  __syncthreads();
  if (tid < 256) {
    const int r = tid >> 2, hh = tid & 3;
    const long row = abase + r;
    if (row < NN) {
      el[row * 4 + hh] = ep_el[2 * hh][r] + ep_el[2 * hh + 1][r];
      er[row * 4 + hh] = ep_er[2 * hh][r] + ep_er[2 * hh + 1][r];
    }
  }
}

// ---------------- fused edge-softmax + aggregation (proven 94us form) -------
// One wave per dst node. At the per-CU outstanding-miss wall (~305MB
// compulsory per-XCD fetch, ~3.9 TB/s demand): deeper pipelining (R1),
// column split (R2), and line-granular XCD-striped split (R4) all failed to
// beat it. Accepted as floor.
template <int MODE>
__global__ __launch_bounds__(256) void aggregate(
    const u16* __restrict__ h, const float* __restrict__ el,
    const float* __restrict__ er, const int* __restrict__ rowp,
    const int* __restrict__ csrs, u16* __restrict__ ob, float* __restrict__ of) {
  __shared__ float w_s[4][64][4];   // [wave][edge][head], 4 KB
  const int wv = threadIdx.x >> 6, lane = threadIdx.x & 63;
  const int n = blockIdx.x * 4 + wv;
  if (n >= NN) return;
  const int base = rowp[n];
  const int deg = rowp[n + 1] - base;
  const int head = lane >> 4;

  if (deg == 0) {  // empty segment: rst row = 0 -> relu -> 0
    if (MODE == 0) {
      short8 z = {};
      *(short8*)(ob + (long)n * HD + lane * 8) = z;
    } else if (lane < 16) {
      floatx4 z = {};
      __builtin_nontemporal_store(z, (floatx4*)(of + (long)n * DD + lane * 8));
      __builtin_nontemporal_store(z, (floatx4*)(of + (long)n * DD + lane * 8 + 4));
    }
    return;
  }

  const floatx4 er4 = *(const floatx4*)(er + n * 4);

  float acc[8] = {0.f, 0.f, 0.f, 0.f, 0.f, 0.f, 0.f, 0.f};
  float sm0 = 0.f, sm1 = 0.f, sm2 = 0.f, sm3 = 0.f;

  for (int c0 = 0; c0 < deg; c0 += 64) {
    const int cnt = min(deg - c0, 64);

    // ---- pass 1: lane-parallel edge metadata ----
    const int l = c0 + lane;
    const int idx = csrs[base + ((l < deg) ? l : (deg - 1))];
    const floatx4 el4 = *(const floatx4*)(el + (long)idx * 4);
    floatx4 w4;
#pragma unroll
    for (int j = 0; j < 4; ++j) {
      float e = el4[j] + er4[j];
      e = (e > 0.f) ? e : 0.2f * e;
      w4[j] = (l < deg) ? __expf(e) : 0.f;
    }
    sm0 += w4[0];
    sm1 += w4[1];
    sm2 += w4[2];
    sm3 += w4[3];
    *(floatx4*)(&w_s[wv][lane][0]) = w4;
    // same-wave LDS write->read: compiler inserts lgkmcnt wait, no barrier.

    // ---- pass 2: deep-pipelined gather, 8 rows in flight ----
    for (int i = 0; i < cnt; i += 8) {
      short8 hv[8];
#pragma unroll
      for (int u = 0; u < 8; ++u) {
        const int s = __builtin_amdgcn_readlane(idx, i + u);
        hv[u] = *(const short8*)(h + (long)s * HD + lane * 8);
      }
#pragma unroll
      for (int u = 0; u < 8; ++u) {
        const float w = w_s[wv][i + u][head];
#pragma unroll
        for (int j = 0; j < 8; ++j) acc[j] += w * b2f((u16)hv[u][j]);
      }
    }
  }

  // sm: butterfly-reduce the 4 per-head partial sums, then pick own head's.
#pragma unroll
  for (int m = 1; m < 64; m <<= 1) {
    sm0 += __shfl_xor(sm0, m, 64);
    sm1 += __shfl_xor(sm1, m, 64);
    sm2 += __shfl_xor(sm2, m, 64);
    sm3 += __shfl_xor(sm3, m, 64);
  }
  const float sm = (head == 0) ? sm0 : (head == 1) ? sm1 : (head == 2) ? sm2 : sm3;

  const float inv = 1.f / sm;
#pragma unroll
  for (int j = 0; j < 8; ++j) acc[j] = fmaxf(acc[j] * inv, 0.f);  // norm + relu

  if (MODE == 0) {
    u16 ub[8];
#pragma unroll
    for (int j = 0; j < 8; ++j) ub[j] = f2b(acc[j]);
    *(short8*)(ob + (long)n * HD + lane * 8) = *(short8*)ub;
  } else {
    // mean over heads: reduce across lane bits 4,5 (head index)
#pragma unroll
    for (int j = 0; j < 8; ++j) acc[j] += __shfl_xor(acc[j], 16, 64);
#pragma unroll
    for (int j = 0; j < 8; ++j) acc[j] += __shfl_xor(acc[j], 32, 64);
    if (lane < 16) {
      floatx4 o0, o1;
#pragma unroll
      for (int j = 0; j < 4; ++j) o0[j] = acc[j] * 0.25f;
#pragma unroll
      for (int j = 0; j < 4; ++j) o1[j] = acc[4 + j] * 0.25f;
      __builtin_nontemporal_store(o0, (floatx4*)(of + (long)n * DD + lane * 8));
      __builtin_nontemporal_store(o1, (floatx4*)(of + (long)n * DD + lane * 8 + 4));
    }
  }
}

extern "C" void kernel_launch(void* const* d_in, const int* in_sizes, int n_in,
                              void* d_out, int out_size, void* d_ws, size_t ws_size,
                              hipStream_t stream) {
  const float* x = (const float*)d_in[0];
  const int* src = (const int*)d_in[1];
  const int* dst = (const int*)d_in[2];
  const float* W0 = (const float*)d_in[3];
  const float* al0 = (const float*)d_in[4];
  const float* ar0 = (const float*)d_in[5];
  const float* W1 = (const float*)d_in[6];
  const float* al1 = (const float*)d_in[7];
  const float* ar1 = (const float*)d_in[8];
  float* out = (float*)d_out;

  char* p = (char*)d_ws;
  u16* h = (u16*)p;        p += (size_t)NN * HD * 2;   // 51.2 MB (bf16)
  u16* rst0 = (u16*)p;     p += (size_t)NN * HD * 2;   // 51.2 MB
  float* el = (float*)p;   p += (size_t)NN * 4 * 4;
  float* er = (float*)p;   p += (size_t)NN * 4 * 4;
  u16* Wt0 = (u16*)p;      p += 512 * 256 * 2;
  u16* Wt1 = (u16*)p;      p += 512 * 512 * 2;
  int* counts = (int*)p;   p += (size_t)NN * 4;
  int* cursor = (int*)p;   p += (size_t)NN * 4;
  int* rowp = (int*)p;     p += (size_t)(NN + 1) * 4;
  int* bsums = (int*)p;    p += 256 * 4;
  int* csrs = (int*)p;     p += (size_t)NE * 4;

  // xb (bf16 x, 25.6MB) overlays rst0 (dead until aggregate<0> writes it,
  // which happens after GEMM1 has consumed xb).
  u16* xb = rst0;

  zero_k<<<NB, 256, 0, stream>>>(counts, NN);
  count_k<<<(NE + 255) / 256, 256, 0, stream>>>(dst, counts);
  blockscan_k<<<NB, 256, 0, stream>>>(counts, rowp, bsums);
  addoff_k<<<NB, 256, 0, stream>>>(rowp, cursor, bsums);
  scatter_k<<<(NE + 255) / 256, 256, 0, stream>>>(src, dst, cursor, csrs);
  prep_k<<<(NN * 256) / 1024 + 512 + 1024, 256, 0, stream>>>(
      x, xb, W0, Wt0, W1, Wt1);

  const int gblocks = (NN + 63) / 64;  // 782
  gemm_el_er<256><<<gblocks, 512, 0, stream>>>(xb, Wt0, al0, ar0, h, el, er);
  aggregate<0><<<(NN + 3) / 4, 256, 0, stream>>>(h, el, er, rowp, csrs, rst0, nullptr);
  gemm_el_er<512><<<gblocks, 512, 0, stream>>>(rst0, Wt1, al1, ar1, h, el, er);
  aggregate<1><<<(NN + 3) / 4, 256, 0, stream>>>(h, el, er, rowp, csrs, nullptr, out);
}